// Round 1
// baseline (1425.101 us; speedup 1.0000x reference)
//
#include <hip/hip_runtime.h>
#include <math.h>

#define BQ 4
#define SEQ 1024
#define EMB 1024
#define NH 16
#define DH 64
#define LN_EPS 1e-3f

// ---------------------------------------------------------------------------
// fp32 tiled GEMM: C[M,1024] = A[M,1024] @ W[1024,1024] (+ residual)
// BM=BN=64, BK=16, 256 threads, 4x4 microtile per thread.
// ---------------------------------------------------------------------------
template <bool ADD_RES>
__global__ __launch_bounds__(256) void gemm_f32(
    const float* __restrict__ A, const float* __restrict__ W,
    const float* __restrict__ res, float* __restrict__ C, int M) {
  const int N = 1024, K = 1024;
  __shared__ __align__(16) float As[16][68];  // [k][m], pad 68: 2-way max on stores
  __shared__ __align__(16) float Bs[16][68];  // [k][n]

  const int bm0 = blockIdx.y * 64;
  const int bn0 = blockIdx.x * 64;
  const int tid = threadIdx.x;
  const int ttm = tid >> 4;  // 0..15
  const int ttn = tid & 15;  // 0..15

  float acc[4][4];
#pragma unroll
  for (int i = 0; i < 4; ++i)
#pragma unroll
    for (int j = 0; j < 4; ++j) acc[i][j] = 0.f;

  for (int k0 = 0; k0 < K; k0 += 16) {
    // A tile: 64 rows x 16 k. thread t: row=t/4, kq=t%4 loads float4 along k.
    {
      const int row = tid >> 2, kq = tid & 3;
      const float4 a4 =
          *(const float4*)&A[(size_t)(bm0 + row) * K + k0 + kq * 4];
      As[kq * 4 + 0][row] = a4.x;
      As[kq * 4 + 1][row] = a4.y;
      As[kq * 4 + 2][row] = a4.z;
      As[kq * 4 + 3][row] = a4.w;
    }
    // B tile: 16 k x 64 n. thread t: kk=t/16, n4=t%16.
    {
      const int kk = tid >> 4, n4 = tid & 15;
      *(float4*)&Bs[kk][n4 * 4] =
          *(const float4*)&W[(size_t)(k0 + kk) * N + bn0 + n4 * 4];
    }
    __syncthreads();
#pragma unroll
    for (int kk = 0; kk < 16; ++kk) {
      const float4 a4 = *(const float4*)&As[kk][ttm * 4];
      const float4 b4 = *(const float4*)&Bs[kk][ttn * 4];
      const float a[4] = {a4.x, a4.y, a4.z, a4.w};
      const float b[4] = {b4.x, b4.y, b4.z, b4.w};
#pragma unroll
      for (int i = 0; i < 4; ++i)
#pragma unroll
        for (int j = 0; j < 4; ++j) acc[i][j] += a[i] * b[j];
    }
    __syncthreads();
  }

#pragma unroll
  for (int i = 0; i < 4; ++i) {
    const size_t roff = (size_t)(bm0 + ttm * 4 + i) * N + bn0 + ttn * 4;
    float4 o = make_float4(acc[i][0], acc[i][1], acc[i][2], acc[i][3]);
    if (ADD_RES) {
      const float4 rv = *(const float4*)&res[roff];
      o.x += rv.x;
      o.y += rv.y;
      o.z += rv.z;
      o.w += rv.w;
    }
    *(float4*)&C[roff] = o;
  }
}

// ---------------------------------------------------------------------------
// Flash attention with Transformer-XL relative position.
// score(i,j) = [ (q_i+rwb)·k_j + (q_i+rrb)·rp_{Q-1-(i-j)} ] / 32,  j <= i.
// One block = one (b, head, 32-row q tile). 256 threads.
// Thread t: row iLoc = t>>3, score cols cc*4..cc*4+3 (cc = t&7);
// PV d-slice d = cc*8..cc*8+7.
// ---------------------------------------------------------------------------
__global__ __launch_bounds__(256) void attn_kernel(
    const float* qbuf, const float* __restrict__ kbuf,
    const float* __restrict__ vbuf, const float* __restrict__ rpbuf,
    const float* __restrict__ rwb, const float* __restrict__ rrb,
    float* obuf) {
  __shared__ __align__(16) float qw[32][68];
  __shared__ __align__(16) float qr[32][68];
  __shared__ __align__(16) float ks[32][68];
  __shared__ __align__(16) float vs[32][68];
  __shared__ __align__(16) float rs[63][68];
  __shared__ __align__(16) float pt[32][36];

  const int i0 = blockIdx.x * 32;
  const int n = blockIdx.y;
  const int b = blockIdx.z;
  const int tid = threadIdx.x;
  const int iLoc = tid >> 3;  // 0..31
  const int cc = tid & 7;     // 0..7

  // stage q tile, pre-biased both ways
#pragma unroll
  for (int rr = 0; rr < 2; ++rr) {
    const int idx = tid + 256 * rr;
    const int row = idx >> 4, c4 = idx & 15;
    const float4 qv = *(const float4*)&qbuf[((size_t)(b * SEQ + i0 + row) * NH + n) * DH + c4 * 4];
    const float4 bw = *(const float4*)&rwb[n * DH + c4 * 4];
    const float4 br = *(const float4*)&rrb[n * DH + c4 * 4];
    *(float4*)&qw[row][c4 * 4] =
        make_float4(qv.x + bw.x, qv.y + bw.y, qv.z + bw.z, qv.w + bw.w);
    *(float4*)&qr[row][c4 * 4] =
        make_float4(qv.x + br.x, qv.y + br.y, qv.z + br.z, qv.w + br.w);
  }

  float m_i = -1e30f, l_i = 0.f;
  float oacc[8];
#pragma unroll
  for (int d = 0; d < 8; ++d) oacc[d] = 0.f;

  for (int j0 = 0; j0 <= i0; j0 += 32) {
    __syncthreads();  // prior-iter reads done (and q-tile staged, iter 0)
    // stage k, v tiles
#pragma unroll
    for (int rr = 0; rr < 2; ++rr) {
      const int idx = tid + 256 * rr;
      const int row = idx >> 4, c4 = idx & 15;
      const size_t goff = ((size_t)(b * SEQ + j0 + row) * NH + n) * DH + c4 * 4;
      *(float4*)&ks[row][c4 * 4] = *(const float4*)&kbuf[goff];
      *(float4*)&vs[row][c4 * 4] = *(const float4*)&vbuf[goff];
    }
    // stage rp band: rows p = pbase .. pbase+62 ; p = Q-1-(i-j)
    const int pbase = SEQ - 32 - i0 + j0;
#pragma unroll
    for (int rr = 0; rr < 4; ++rr) {
      const int idx = tid + 256 * rr;
      if (idx < 63 * 16) {
        const int row = idx >> 4, c4 = idx & 15;
        const int p = pbase + row;
        float4 rv = make_float4(0.f, 0.f, 0.f, 0.f);
        if (p < SEQ)
          rv = *(const float4*)&rpbuf[((size_t)p * NH + n) * DH + c4 * 4];
        *(float4*)&rs[row][c4 * 4] = rv;
      }
    }
    __syncthreads();

    // scores: 4 per thread
    float s[4] = {0.f, 0.f, 0.f, 0.f};
    const int rbase = 31 - iLoc;  // rs row for col jL is rbase + jL
#pragma unroll
    for (int d4 = 0; d4 < 16; ++d4) {
      const float4 a = *(const float4*)&qw[iLoc][d4 * 4];
      const float4 c = *(const float4*)&qr[iLoc][d4 * 4];
#pragma unroll
      for (int jj = 0; jj < 4; ++jj) {
        const int jL = cc * 4 + jj;
        const float4 k4 = *(const float4*)&ks[jL][d4 * 4];
        const float4 r4 = *(const float4*)&rs[rbase + jL][d4 * 4];
        s[jj] += a.x * k4.x + a.y * k4.y + a.z * k4.z + a.w * k4.w +
                 c.x * r4.x + c.y * r4.y + c.z * r4.z + c.w * r4.w;
      }
    }
#pragma unroll
    for (int jj = 0; jj < 4; ++jj) {
      const int j = j0 + cc * 4 + jj;
      const int i = i0 + iLoc;
      s[jj] = (j <= i) ? s[jj] * 0.03125f : -1e30f;
    }
    // online softmax over the 8 lanes sharing this row
    float mloc = fmaxf(fmaxf(s[0], s[1]), fmaxf(s[2], s[3]));
    mloc = fmaxf(mloc, __shfl_xor(mloc, 1));
    mloc = fmaxf(mloc, __shfl_xor(mloc, 2));
    mloc = fmaxf(mloc, __shfl_xor(mloc, 4));
    const float m_new = fmaxf(m_i, mloc);
    const float alpha = __expf(m_i - m_new);
    float p[4], psum = 0.f;
#pragma unroll
    for (int jj = 0; jj < 4; ++jj) {
      p[jj] = __expf(s[jj] - m_new);
      psum += p[jj];
    }
    psum += __shfl_xor(psum, 1);
    psum += __shfl_xor(psum, 2);
    psum += __shfl_xor(psum, 4);
    l_i = l_i * alpha + psum;
    m_i = m_new;
#pragma unroll
    for (int d = 0; d < 8; ++d) oacc[d] *= alpha;
#pragma unroll
    for (int jj = 0; jj < 4; ++jj) pt[iLoc][cc * 4 + jj] = p[jj];
    __syncthreads();  // pt visible (also keeps waves in lockstep for vs reuse)
    // PV: this thread owns d = cc*8 .. cc*8+7 of row iLoc
#pragma unroll
    for (int j = 0; j < 32; ++j) {
      const float pv = pt[iLoc][j];
      const float4 v0 = *(const float4*)&vs[j][cc * 8];
      const float4 v1 = *(const float4*)&vs[j][cc * 8 + 4];
      oacc[0] += pv * v0.x;
      oacc[1] += pv * v0.y;
      oacc[2] += pv * v0.z;
      oacc[3] += pv * v0.w;
      oacc[4] += pv * v1.x;
      oacc[5] += pv * v1.y;
      oacc[6] += pv * v1.z;
      oacc[7] += pv * v1.w;
    }
  }

  const float inv_l = 1.0f / l_i;
  const size_t orow = ((size_t)(b * SEQ + i0 + iLoc) * NH + n) * DH;
  const float4 o0 = make_float4(oacc[0] * inv_l, oacc[1] * inv_l,
                                oacc[2] * inv_l, oacc[3] * inv_l);
  const float4 o1 = make_float4(oacc[4] * inv_l, oacc[5] * inv_l,
                                oacc[6] * inv_l, oacc[7] * inv_l);
  *(float4*)&obuf[orow + cc * 8] = o0;
  *(float4*)&obuf[orow + cc * 8 + 4] = o1;
}

// ---------------------------------------------------------------------------
// LayerNorm over last dim (1024). One block per row.
// ---------------------------------------------------------------------------
__global__ __launch_bounds__(256) void ln_kernel(const float* __restrict__ x,
                                                 const float* __restrict__ gamma,
                                                 const float* __restrict__ beta,
                                                 float* __restrict__ out) {
  const int row = blockIdx.x;
  const int tid = threadIdx.x;
  const float4 xv = *(const float4*)&x[(size_t)row * EMB + tid * 4];
  float sum = xv.x + xv.y + xv.z + xv.w;
  float ss = xv.x * xv.x + xv.y * xv.y + xv.z * xv.z + xv.w * xv.w;
#pragma unroll
  for (int off = 1; off < 64; off <<= 1) {
    sum += __shfl_xor(sum, off);
    ss += __shfl_xor(ss, off);
  }
  __shared__ float s1[4], s2[4];
  if ((tid & 63) == 0) {
    s1[tid >> 6] = sum;
    s2[tid >> 6] = ss;
  }
  __syncthreads();
  sum = s1[0] + s1[1] + s1[2] + s1[3];
  ss = s2[0] + s2[1] + s2[2] + s2[3];
  const float mu = sum * (1.f / EMB);
  const float var = ss * (1.f / EMB) - mu * mu;
  const float rstd = rsqrtf(var + LN_EPS);
  const float4 g = *(const float4*)&gamma[tid * 4];
  const float4 be = *(const float4*)&beta[tid * 4];
  float4 o;
  o.x = (xv.x - mu) * rstd * g.x + be.x;
  o.y = (xv.y - mu) * rstd * g.y + be.y;
  o.z = (xv.z - mu) * rstd * g.z + be.z;
  o.w = (xv.w - mu) * rstd * g.w + be.w;
  *(float4*)&out[(size_t)row * EMB + tid * 4] = o;
}

extern "C" void kernel_launch(void* const* d_in, const int* in_sizes, int n_in,
                              void* d_out, int out_size, void* d_ws,
                              size_t ws_size, hipStream_t stream) {
  const float* w = (const float*)d_in[0];
  const float* r = (const float*)d_in[1];
  const float* rwb = (const float*)d_in[2];
  const float* rrb = (const float*)d_in[3];
  // d_in[4] attn_mask: causality computed analytically
  const float* Wq = (const float*)d_in[5];
  const float* Wk = (const float*)d_in[6];
  const float* Wv = (const float*)d_in[7];
  const float* Wr = (const float*)d_in[8];
  const float* Wo = (const float*)d_in[9];
  const float* gamma = (const float*)d_in[10];
  const float* beta = (const float*)d_in[11];
  float* outp = (float*)d_out;

  float* ws = (float*)d_ws;
  float* qbuf = ws;                        // 4M floats (o aliases q: safe,
  float* kbuf = qbuf + 4 * 1024 * 1024;    //   q rows are block-private)
  float* vbuf = kbuf + 4 * 1024 * 1024;    // 4M
  float* rpbuf = vbuf + 4 * 1024 * 1024;   // 1M; total 13M floats = 52 MB
  float* ybuf = kbuf;                      // k is dead after attention

  const dim3 blk(256);
  const dim3 gW(16, 64);  // N/64 x M/64, M=4096
  gemm_f32<false><<<gW, blk, 0, stream>>>(w, Wq, nullptr, qbuf, 4096);
  gemm_f32<false><<<gW, blk, 0, stream>>>(w, Wk, nullptr, kbuf, 4096);
  gemm_f32<false><<<gW, blk, 0, stream>>>(w, Wv, nullptr, vbuf, 4096);
  gemm_f32<false><<<dim3(16, 16), blk, 0, stream>>>(r, Wr, nullptr, rpbuf, 1024);

  attn_kernel<<<dim3(SEQ / 32, NH, BQ), blk, 0, stream>>>(qbuf, kbuf, vbuf,
                                                          rpbuf, rwb, rrb,
                                                          /*obuf=*/qbuf);

  gemm_f32<true><<<gW, blk, 0, stream>>>(qbuf, Wo, w, ybuf, 4096);
  ln_kernel<<<BQ * SEQ, blk, 0, stream>>>(ybuf, gamma, beta, outp);
}

// Round 2
// 364.772 us; speedup vs baseline: 3.9068x; 3.9068x over previous
//
#include <hip/hip_runtime.h>
#include <math.h>

#define BQ 4
#define SEQ 1024
#define EMB 1024
#define NH 16
#define DH 64
#define LN_EPS 1e-3f

typedef unsigned short u16;
typedef __attribute__((ext_vector_type(8))) unsigned short ushort8;
typedef __attribute__((ext_vector_type(4))) unsigned short ushort4v;
typedef __attribute__((ext_vector_type(8))) __bf16 bf16x8;
typedef __attribute__((ext_vector_type(4))) float f32x4;

__device__ __forceinline__ u16 f2bf(float f) {
  union { float f; unsigned u; } v;
  v.f = f;
  unsigned u = v.u;
  u += 0x7FFF + ((u >> 16) & 1);  // RNE
  return (u16)(u >> 16);
}
__device__ __forceinline__ float bf2f(u16 h) {
  union { unsigned u; float f; } v;
  v.u = ((unsigned)h) << 16;
  return v.f;
}
__device__ __forceinline__ bf16x8 as_bf(ushort8 v) {
  union { ushort8 u; bf16x8 b; } x;
  x.u = v;
  return x.b;
}
__device__ __forceinline__ f32x4 mfma16(ushort8 a, ushort8 b, f32x4 c) {
  return __builtin_amdgcn_mfma_f32_16x16x32_bf16(as_bf(a), as_bf(b), c, 0, 0, 0);
}
// async global->LDS, 16B per lane (lds dest must be wave-uniform base + lane*16)
__device__ __forceinline__ void gload16(const u16* g, u16* l) {
  __builtin_amdgcn_global_load_lds(
      (const __attribute__((address_space(1))) void*)g,
      (__attribute__((address_space(3))) void*)l, 16, 0, 0);
}

// ---------------------------------------------------------------------------
// fp32 -> bf16 elementwise (4 elems/thread)
// ---------------------------------------------------------------------------
__global__ __launch_bounds__(256) void f2bf_kernel(const float* __restrict__ src,
                                                   u16* __restrict__ dst) {
  const int idx = (blockIdx.x * 256 + threadIdx.x) * 4;
  const float4 v = *(const float4*)&src[idx];
  ushort4v o;
  o[0] = f2bf(v.x);
  o[1] = f2bf(v.y);
  o[2] = f2bf(v.z);
  o[3] = f2bf(v.w);
  *(ushort4v*)&dst[idx] = o;
}

// ---------------------------------------------------------------------------
// 1024x1024 fp32 -> bf16 transposed: dst[n][k] = src[k][n]
// ---------------------------------------------------------------------------
__global__ __launch_bounds__(256) void transpose_f2bf(const float* __restrict__ src,
                                                      u16* __restrict__ dst) {
  __shared__ u16 tile[32][33];
  const int tid = threadIdx.x;
  const int k0 = blockIdx.y * 32, n0 = blockIdx.x * 32;
  const int r = tid >> 3, c4 = tid & 7;
  const float4 v = *(const float4*)&src[(size_t)(k0 + r) * 1024 + n0 + c4 * 4];
  tile[r][c4 * 4 + 0] = f2bf(v.x);
  tile[r][c4 * 4 + 1] = f2bf(v.y);
  tile[r][c4 * 4 + 2] = f2bf(v.z);
  tile[r][c4 * 4 + 3] = f2bf(v.w);
  __syncthreads();
  ushort4v o;
#pragma unroll
  for (int e = 0; e < 4; ++e) o[e] = tile[c4 * 4 + e][r];
  *(ushort4v*)&dst[(size_t)(n0 + r) * 1024 + k0 + c4 * 4] = o;
}

// ---------------------------------------------------------------------------
// bf16 MFMA GEMM (m97 pattern): C[M,N] = A[M,1024] @ B^T, B given as [N][1024].
// 128x128 tile, BK=32, 256 thr = 4 waves in 2x2, each wave 64x64 (4x4 MFMA tiles).
// ---------------------------------------------------------------------------
template <bool OUT_BF16, bool ADD_RES>
__global__ __launch_bounds__(256) void gemm_bf16(
    const u16* __restrict__ A, const u16* __restrict__ Bt,
    const float* __restrict__ res, void* __restrict__ Cp, int Nld) {
  __shared__ u16 As[128 * 32];
  __shared__ u16 Bs[128 * 32];
  const int tid = threadIdx.x;
  const int quad = (tid >> 4) & 3, colL = tid & 15;
  const int wv = tid >> 6;
  const int wr = wv >> 1, wc = wv & 1;
  const int bm0 = blockIdx.y * 128, bn0 = blockIdx.x * 128;

  f32x4 acc[4][4] = {};
  for (int k0 = 0; k0 < 1024; k0 += 32) {
#pragma unroll
    for (int rr = 0; rr < 2; ++rr) {
      const int c = rr * 256 + tid;  // chunk id; per-wave lds dest is contiguous
      const int row = c >> 2, kc = c & 3;
      gload16(&A[(size_t)(bm0 + row) * 1024 + k0 + kc * 8], &As[c * 8]);
      gload16(&Bt[(size_t)(bn0 + row) * 1024 + k0 + kc * 8], &Bs[c * 8]);
    }
    __syncthreads();  // drains vmcnt -> LDS tiles ready
    ushort8 af[4], bf[4];
#pragma unroll
    for (int t = 0; t < 4; ++t) {
      af[t] = *(const ushort8*)&As[(wr * 64 + t * 16 + colL) * 32 + quad * 8];
      bf[t] = *(const ushort8*)&Bs[(wc * 64 + t * 16 + colL) * 32 + quad * 8];
    }
#pragma unroll
    for (int i = 0; i < 4; ++i)
#pragma unroll
      for (int j = 0; j < 4; ++j) acc[i][j] = mfma16(af[i], bf[j], acc[i][j]);
    __syncthreads();
  }

#pragma unroll
  for (int i = 0; i < 4; ++i) {
    const int grow0 = bm0 + wr * 64 + i * 16 + quad * 4;
#pragma unroll
    for (int j = 0; j < 4; ++j) {
      const int gcol = bn0 + wc * 64 + j * 16 + colL;
#pragma unroll
      for (int e = 0; e < 4; ++e) {
        const size_t off = (size_t)(grow0 + e) * Nld + gcol;
        if (OUT_BF16) {
          ((u16*)Cp)[off] = f2bf(acc[i][j][e]);
        } else {
          float v = acc[i][j][e];
          if (ADD_RES) v += res[off];
          ((float*)Cp)[off] = v;
        }
      }
    }
  }
}

// ---------------------------------------------------------------------------
// MFMA flash attention with Transformer-XL relative position.
// Block = (i-tile of 64 rows, head, batch), 256 thr = 4 waves; wave w owns
// q-rows 16w..16w+15 for the whole flash loop (softmax stays wave-local).
// Per 64-wide j-tile:
//   AC  = (q+rwb) @ k^T                       (MFMA, ks[j][d])
//   Btl = (q+rrb) @ rp_band^T  (128-wide band; BD[i,j] = Btl[i][63+jL-iL])
//   gather Btl diag + mask + online softmax -> P (bf16, LDS)
//   O  += P @ V                               (MFMA, vs[d][j] transposed)
// All bf16 LDS tiles stride 72 (2-way conflicts only).
// ---------------------------------------------------------------------------
__global__ __launch_bounds__(256) void attn_mfma(
    const u16* __restrict__ qkv,  // [4096][3072]  q|k|v
    const u16* __restrict__ rp,   // [1024][1024]
    const float* __restrict__ rwb, const float* __restrict__ rrb,
    u16* __restrict__ obuf) {  // [4096][1024]
  __shared__ u16 ks[64 * 72];
  __shared__ u16 vs[64 * 72];  // transposed [d][j]
  __shared__ u16 rs[128 * 72];
  __shared__ u16 Ps[64 * 72];
  __shared__ u16 Btl[64 * 136];

  const int i0 = blockIdx.x * 64;
  const int hn = blockIdx.y;
  const int b = blockIdx.z;
  const int tid = threadIdx.x;
  const int wv = tid >> 6;
  const int quad = (tid >> 4) & 3, colL = tid & 15;

  // q fragments with both biases, kh in {0,1} covers d=0..63
  ushort8 qw[2], qr[2];
  {
    const size_t qrow = (size_t)(b * SEQ + i0 + wv * 16 + colL) * 3072;
#pragma unroll
    for (int kh = 0; kh < 2; ++kh) {
      const int dof = hn * 64 + kh * 32 + quad * 8;
      const ushort8 qv = *(const ushort8*)&qkv[qrow + dof];
      const float4 w0 = *(const float4*)&rwb[dof];
      const float4 w1 = *(const float4*)&rwb[dof + 4];
      const float4 r0 = *(const float4*)&rrb[dof];
      const float4 r1 = *(const float4*)&rrb[dof + 4];
      const float wb[8] = {w0.x, w0.y, w0.z, w0.w, w1.x, w1.y, w1.z, w1.w};
      const float rb[8] = {r0.x, r0.y, r0.z, r0.w, r1.x, r1.y, r1.z, r1.w};
#pragma unroll
      for (int e = 0; e < 8; ++e) {
        const float qf = bf2f(qv[e]);
        qw[kh][e] = f2bf(qf + wb[e]);
        qr[kh][e] = f2bf(qf + rb[e]);
      }
    }
  }

  f32x4 oacc[4] = {};
  float m_st[4], l_st[4];
#pragma unroll
  for (int r = 0; r < 4; ++r) {
    m_st[r] = -1e30f;
    l_st[r] = 0.f;
  }

  for (int j0 = 0; j0 <= i0; j0 += 64) {
    __syncthreads();  // prev-iter vs/Ps reads complete before restage
    // stage k (natural) and v (transposed)
#pragma unroll
    for (int rr = 0; rr < 2; ++rr) {
      const int c = rr * 256 + tid;
      const int j = c >> 3, dc = c & 7;
      const size_t grow = (size_t)(b * SEQ + j0 + j) * 3072 + hn * 64 + dc * 8;
      const ushort8 kk = *(const ushort8*)&qkv[grow + 1024];
      const ushort8 vvv = *(const ushort8*)&qkv[grow + 2048];
      *(ushort8*)&ks[j * 72 + dc * 8] = kk;
#pragma unroll
      for (int e = 0; e < 8; ++e) vs[(dc * 8 + e) * 72 + j] = vvv[e];
    }
    // stage rp band: rs[t][d], p = pbase + t, t in [0,128)
    const int pbase = SEQ - 64 - i0 + j0;
#pragma unroll
    for (int rr = 0; rr < 4; ++rr) {
      const int c = rr * 256 + tid;
      const int t = c >> 3, dc = c & 7;
      const int p = pbase + t;
      ushort8 rv;
      if (p < SEQ) {
        rv = *(const ushort8*)&rp[(size_t)p * 1024 + hn * 64 + dc * 8];
      } else {
#pragma unroll
        for (int e = 0; e < 8; ++e) rv[e] = 0;
      }
      *(ushort8*)&rs[t * 72 + dc * 8] = rv;
    }
    __syncthreads();

    // AC: 16x64 per wave
    f32x4 sAC[4] = {};
#pragma unroll
    for (int jt = 0; jt < 4; ++jt)
#pragma unroll
      for (int kh = 0; kh < 2; ++kh)
        sAC[jt] = mfma16(
            qw[kh],
            *(const ushort8*)&ks[(jt * 16 + colL) * 72 + kh * 32 + quad * 8],
            sAC[jt]);
    // BD band: 16x128 per wave -> Btl
    {
      f32x4 bd[8] = {};
#pragma unroll
      for (int tt = 0; tt < 8; ++tt)
#pragma unroll
        for (int kh = 0; kh < 2; ++kh)
          bd[tt] = mfma16(
              qr[kh],
              *(const ushort8*)&rs[(tt * 16 + colL) * 72 + kh * 32 + quad * 8],
              bd[tt]);
#pragma unroll
      for (int tt = 0; tt < 8; ++tt)
#pragma unroll
        for (int e = 0; e < 4; ++e)
          Btl[(wv * 16 + quad * 4 + e) * 136 + tt * 16 + colL] =
              f2bf(bd[tt][e]);
    }
    __syncthreads();

    // gather diag + mask + online softmax; write P (bf16)
#pragma unroll
    for (int r = 0; r < 4; ++r) {
      const int iLt = wv * 16 + quad * 4 + r;
      const int ig = i0 + iLt;
      float s[4];
#pragma unroll
      for (int jt = 0; jt < 4; ++jt) {
        const int jL = jt * 16 + colL;
        const float bdv = bf2f(Btl[iLt * 136 + 63 + jL - iLt]);
        s[jt] = (j0 + jL <= ig) ? (sAC[jt][r] + bdv) * 0.03125f : -1e30f;
      }
      float mx = fmaxf(fmaxf(s[0], s[1]), fmaxf(s[2], s[3]));
      mx = fmaxf(mx, __shfl_xor(mx, 1));
      mx = fmaxf(mx, __shfl_xor(mx, 2));
      mx = fmaxf(mx, __shfl_xor(mx, 4));
      mx = fmaxf(mx, __shfl_xor(mx, 8));
      const float m_new = fmaxf(m_st[r], mx);
      const float alpha = __expf(m_st[r] - m_new);
      float ps = 0.f;
#pragma unroll
      for (int jt = 0; jt < 4; ++jt) {
        const float pv = __expf(s[jt] - m_new);
        ps += pv;
        Ps[iLt * 72 + jt * 16 + colL] = f2bf(pv);
      }
      ps += __shfl_xor(ps, 1);
      ps += __shfl_xor(ps, 2);
      ps += __shfl_xor(ps, 4);
      ps += __shfl_xor(ps, 8);
      l_st[r] = l_st[r] * alpha + ps;
      m_st[r] = m_new;
#pragma unroll
      for (int dt = 0; dt < 4; ++dt) oacc[dt][r] *= alpha;
    }
    __syncthreads();

    // PV: O += P @ V
#pragma unroll
    for (int dt = 0; dt < 4; ++dt)
#pragma unroll
      for (int kh = 0; kh < 2; ++kh)
        oacc[dt] = mfma16(
            *(const ushort8*)&Ps[(wv * 16 + colL) * 72 + kh * 32 + quad * 8],
            *(const ushort8*)&vs[(dt * 16 + colL) * 72 + kh * 32 + quad * 8],
            oacc[dt]);
  }

  // epilogue: O /= l, write bf16 [b*1024+i][hn*64+d]
#pragma unroll
  for (int r = 0; r < 4; ++r) {
    const float invl = 1.0f / l_st[r];
    const size_t grow =
        (size_t)(b * SEQ + i0 + wv * 16 + quad * 4 + r) * 1024 + hn * 64;
#pragma unroll
    for (int dt = 0; dt < 4; ++dt)
      obuf[grow + dt * 16 + colL] = f2bf(oacc[dt][r] * invl);
  }
}

// ---------------------------------------------------------------------------
// LayerNorm over last dim (1024), in-place safe. One block per row.
// ---------------------------------------------------------------------------
__global__ __launch_bounds__(256) void ln_kernel(const float* __restrict__ x,
                                                 const float* __restrict__ gamma,
                                                 const float* __restrict__ beta,
                                                 float* __restrict__ out) {
  const int row = blockIdx.x;
  const int tid = threadIdx.x;
  const float4 xv = *(const float4*)&x[(size_t)row * EMB + tid * 4];
  float sum = xv.x + xv.y + xv.z + xv.w;
  float ss = xv.x * xv.x + xv.y * xv.y + xv.z * xv.z + xv.w * xv.w;
#pragma unroll
  for (int off = 1; off < 64; off <<= 1) {
    sum += __shfl_xor(sum, off);
    ss += __shfl_xor(ss, off);
  }
  __shared__ float s1[4], s2[4];
  if ((tid & 63) == 0) {
    s1[tid >> 6] = sum;
    s2[tid >> 6] = ss;
  }
  __syncthreads();
  sum = s1[0] + s1[1] + s1[2] + s1[3];
  ss = s2[0] + s2[1] + s2[2] + s2[3];
  const float mu = sum * (1.f / EMB);
  const float var = ss * (1.f / EMB) - mu * mu;
  const float rstd = rsqrtf(var + LN_EPS);
  const float4 g = *(const float4*)&gamma[tid * 4];
  const float4 be = *(const float4*)&beta[tid * 4];
  float4 o;
  o.x = (xv.x - mu) * rstd * g.x + be.x;
  o.y = (xv.y - mu) * rstd * g.y + be.y;
  o.z = (xv.z - mu) * rstd * g.z + be.z;
  o.w = (xv.w - mu) * rstd * g.w + be.w;
  *(float4*)&out[(size_t)row * EMB + tid * 4] = o;
}

extern "C" void kernel_launch(void* const* d_in, const int* in_sizes, int n_in,
                              void* d_out, int out_size, void* d_ws,
                              size_t ws_size, hipStream_t stream) {
  const float* w = (const float*)d_in[0];
  const float* r = (const float*)d_in[1];
  const float* rwb = (const float*)d_in[2];
  const float* rrb = (const float*)d_in[3];
  // d_in[4] attn_mask: causality handled analytically
  const float* Wq = (const float*)d_in[5];
  const float* Wk = (const float*)d_in[6];
  const float* Wv = (const float*)d_in[7];
  const float* Wr = (const float*)d_in[8];
  const float* Wo = (const float*)d_in[9];
  const float* gamma = (const float*)d_in[10];
  const float* beta = (const float*)d_in[11];
  float* outp = (float*)d_out;

  char* wsb = (char*)d_ws;
  u16* wbf = (u16*)(wsb);                          // 8 MB  [0,8)
  u16* rbf = (u16*)(wsb + ((size_t)8 << 20));      // 2 MB  [8,10)
  u16* WqkvT = (u16*)(wsb + ((size_t)10 << 20));   // 6 MB  [10,16)
  u16* WrT = (u16*)(wsb + ((size_t)16 << 20));     // 2 MB  [16,18)
  u16* WoT = (u16*)(wsb + ((size_t)18 << 20));     // 2 MB  [18,20)
  u16* qkv = (u16*)(wsb + ((size_t)20 << 20));     // 24 MB [20,44)
  u16* rpb = (u16*)(wsb + ((size_t)44 << 20));     // 2 MB  [44,46)
  u16* obuf = (u16*)(wsb + ((size_t)10 << 20));    // 8 MB overlay [10,18):
                                                   // WqkvT/WrT dead pre-attn

  const dim3 blk(256);
  f2bf_kernel<<<4096, blk, 0, stream>>>(w, wbf);
  f2bf_kernel<<<1024, blk, 0, stream>>>(r, rbf);
  transpose_f2bf<<<dim3(32, 32), blk, 0, stream>>>(Wq, WqkvT);
  transpose_f2bf<<<dim3(32, 32), blk, 0, stream>>>(Wk, WqkvT + 1024 * 1024);
  transpose_f2bf<<<dim3(32, 32), blk, 0, stream>>>(Wv, WqkvT + 2 * 1024 * 1024);
  transpose_f2bf<<<dim3(32, 32), blk, 0, stream>>>(Wr, WrT);
  transpose_f2bf<<<dim3(32, 32), blk, 0, stream>>>(Wo, WoT);

  gemm_bf16<true, false><<<dim3(24, 32), blk, 0, stream>>>(wbf, WqkvT, nullptr,
                                                           qkv, 3072);
  gemm_bf16<true, false><<<dim3(8, 8), blk, 0, stream>>>(rbf, WrT, nullptr,
                                                         rpb, 1024);

  attn_mfma<<<dim3(16, 16, 4), blk, 0, stream>>>(qkv, rpb, rwb, rrb, obuf);

  gemm_bf16<false, true><<<dim3(8, 32), blk, 0, stream>>>(obuf, WoT, w,
                                                          (void*)outp, 1024);
  ln_kernel<<<BQ * SEQ, blk, 0, stream>>>(outp, gamma, beta, outp);
}

// Round 3
// 286.903 us; speedup vs baseline: 4.9672x; 1.2714x over previous
//
#include <hip/hip_runtime.h>
#include <math.h>

#define BQ 4
#define SEQ 1024
#define EMB 1024
#define NH 16
#define DH 64
#define LN_EPS 1e-3f

typedef unsigned short u16;
typedef __attribute__((ext_vector_type(8))) unsigned short ushort8;
typedef __attribute__((ext_vector_type(4))) unsigned short ushort4v;
typedef __attribute__((ext_vector_type(8))) __bf16 bf16x8;
typedef __attribute__((ext_vector_type(4))) float f32x4;

__device__ __forceinline__ u16 f2bf(float f) {
  union { float f; unsigned u; } v;
  v.f = f;
  unsigned u = v.u;
  u += 0x7FFF + ((u >> 16) & 1);  // RNE
  return (u16)(u >> 16);
}
__device__ __forceinline__ float bf2f(u16 h) {
  union { unsigned u; float f; } v;
  v.u = ((unsigned)h) << 16;
  return v.f;
}
__device__ __forceinline__ bf16x8 as_bf(ushort8 v) {
  union { ushort8 u; bf16x8 b; } x;
  x.u = v;
  return x.b;
}
__device__ __forceinline__ f32x4 mfma16(ushort8 a, ushort8 b, f32x4 c) {
  return __builtin_amdgcn_mfma_f32_16x16x32_bf16(as_bf(a), as_bf(b), c, 0, 0, 0);
}
__device__ __forceinline__ void gload16(const u16* g, u16* l) {
  __builtin_amdgcn_global_load_lds(
      (const __attribute__((address_space(1))) void*)g,
      (__attribute__((address_space(3))) void*)l, 16, 0, 0);
}

// ---------------------------------------------------------------------------
// fp32 -> bf16: blocks 0..4095 convert w (4M elems), 4096..5119 convert r (1M)
// ---------------------------------------------------------------------------
__global__ __launch_bounds__(256) void f2bf_fused(const float* __restrict__ w,
                                                  const float* __restrict__ r,
                                                  u16* __restrict__ wbf,
                                                  u16* __restrict__ rbf) {
  const int bid = blockIdx.x;
  const float* src = (bid < 4096) ? w : r;
  u16* dst = (bid < 4096) ? wbf : rbf;
  const int base = (bid < 4096) ? bid : bid - 4096;
  const int idx = (base * 256 + threadIdx.x) * 4;
  const float4 v = *(const float4*)&src[idx];
  ushort4v o;
  o[0] = f2bf(v.x);
  o[1] = f2bf(v.y);
  o[2] = f2bf(v.z);
  o[3] = f2bf(v.w);
  *(ushort4v*)&dst[idx] = o;
}

// ---------------------------------------------------------------------------
// 5x fused 1024x1024 fp32 -> bf16 transposed: z selects {Wq,Wk,Wv,Wr,Wo}
// ---------------------------------------------------------------------------
__global__ __launch_bounds__(256) void transpose_f2bf5(
    const float* __restrict__ Wq, const float* __restrict__ Wk,
    const float* __restrict__ Wv, const float* __restrict__ Wr,
    const float* __restrict__ Wo, u16* __restrict__ WqkvT,
    u16* __restrict__ WrT, u16* __restrict__ WoT) {
  __shared__ u16 tile[32][33];
  const int z = blockIdx.z;
  const float* src = (z == 0) ? Wq : (z == 1) ? Wk : (z == 2) ? Wv
                     : (z == 3) ? Wr : Wo;
  u16* dst = (z < 3) ? (WqkvT + (size_t)z * 1024 * 1024)
             : (z == 3) ? WrT : WoT;
  const int tid = threadIdx.x;
  const int k0 = blockIdx.y * 32, n0 = blockIdx.x * 32;
  const int r = tid >> 3, c4 = tid & 7;
  const float4 v = *(const float4*)&src[(size_t)(k0 + r) * 1024 + n0 + c4 * 4];
  tile[r][c4 * 4 + 0] = f2bf(v.x);
  tile[r][c4 * 4 + 1] = f2bf(v.y);
  tile[r][c4 * 4 + 2] = f2bf(v.z);
  tile[r][c4 * 4 + 3] = f2bf(v.w);
  __syncthreads();
  ushort4v o;
#pragma unroll
  for (int e = 0; e < 4; ++e) o[e] = tile[c4 * 4 + e][r];
  *(ushort4v*)&dst[(size_t)(n0 + r) * 1024 + k0 + c4 * 4] = o;
}

// ---------------------------------------------------------------------------
// bf16 MFMA GEMM, 128x128 tile, BK=32, 4 waves.
// MODE 0: fp32 out + residual (Nld cols)
// MODE 1: bf16 out (Nld cols)
// MODE 2: qkv: cols <2048 -> bf16 qk buffer (Nld=2048); cols >=2048 ->
//         V written TRANSPOSED to vT[b*1024 + (col-2048)][seqpos]
// ---------------------------------------------------------------------------
template <int MODE>
__global__ __launch_bounds__(256) void gemm_bf16(
    const u16* __restrict__ A, const u16* __restrict__ Bt,
    const float* __restrict__ res, void* __restrict__ Cp,
    u16* __restrict__ vT, int Nld) {
  __shared__ u16 As[128 * 32];
  __shared__ u16 Bs[128 * 32];
  const int tid = threadIdx.x;
  const int quad = (tid >> 4) & 3, colL = tid & 15;
  const int wv = tid >> 6;
  const int wr = wv >> 1, wc = wv & 1;
  const int bm0 = blockIdx.y * 128, bn0 = blockIdx.x * 128;

  f32x4 acc[4][4] = {};
  for (int k0 = 0; k0 < 1024; k0 += 32) {
#pragma unroll
    for (int rr = 0; rr < 2; ++rr) {
      const int c = rr * 256 + tid;
      const int row = c >> 2, kc = c & 3;
      gload16(&A[(size_t)(bm0 + row) * 1024 + k0 + kc * 8], &As[c * 8]);
      gload16(&Bt[(size_t)(bn0 + row) * 1024 + k0 + kc * 8], &Bs[c * 8]);
    }
    __syncthreads();
    ushort8 af[4], bf[4];
#pragma unroll
    for (int t = 0; t < 4; ++t) {
      af[t] = *(const ushort8*)&As[(wr * 64 + t * 16 + colL) * 32 + quad * 8];
      bf[t] = *(const ushort8*)&Bs[(wc * 64 + t * 16 + colL) * 32 + quad * 8];
    }
#pragma unroll
    for (int i = 0; i < 4; ++i)
#pragma unroll
      for (int j = 0; j < 4; ++j) acc[i][j] = mfma16(af[i], bf[j], acc[i][j]);
    __syncthreads();
  }

  const bool vpart = (MODE == 2) && (bn0 >= 2048);
#pragma unroll
  for (int i = 0; i < 4; ++i) {
    const int grow0 = bm0 + wr * 64 + i * 16 + quad * 4;
#pragma unroll
    for (int j = 0; j < 4; ++j) {
      const int gcol = bn0 + wc * 64 + j * 16 + colL;
      if (vpart) {
        // vT[(grow0>>10)*1024 + (gcol-2048)][grow0&1023 .. +3]
        const size_t base =
            ((size_t)(grow0 >> 10) * 1024 + (gcol - 2048)) * 1024 +
            (grow0 & 1023);
        ushort4v o;
#pragma unroll
        for (int e = 0; e < 4; ++e) o[e] = f2bf(acc[i][j][e]);
        *(ushort4v*)&vT[base] = o;
      } else {
#pragma unroll
        for (int e = 0; e < 4; ++e) {
          const size_t off = (size_t)(grow0 + e) * Nld + gcol;
          if (MODE == 0) {
            ((float*)Cp)[off] = acc[i][j][e] + res[off];
          } else {
            ((u16*)Cp)[off] = f2bf(acc[i][j][e]);
          }
        }
      }
    }
  }
}

// ---------------------------------------------------------------------------
// MFMA flash attention, Transformer-XL relative position.
// Swizzled block decode balances j-loop trip counts across CUs.
// LDS (36 KB): ks 64x72 (alias Ps) | vs 64x72 [d][j] | rs 128x72 (alias Btl
// 64x132). Btl is wave-private (each wave gathers only its own 16 rows), so
// only band tiles tt in [3-wv, 7-wv] are computed (5 per wave).
// ---------------------------------------------------------------------------
__global__ __launch_bounds__(256, 4) void attn_mfma(
    const u16* __restrict__ qk,  // [4096][2048]  q|k
    const u16* __restrict__ vT,  // [4096][1024]  [b*1024+hd][j]
    const u16* __restrict__ rp,  // [1024][1024]
    const float* __restrict__ rwb, const float* __restrict__ rrb,
    u16* __restrict__ obuf) {  // [4096][1024]
  __shared__ u16 smem[18432];
  u16* ks = smem;          // 64x72
  u16* vs = smem + 4608;   // 64x72
  u16* rs = smem + 9216;   // 128x72
  u16* Ps = smem;          // alias ks
  u16* Btl = smem + 9216;  // alias rs, stride 132

  const int L = blockIdx.x;
  const int b = L & 3;
  const int hn = (L >> 2) & 15;
  const int ph = L >> 6;
  const int itile = (ph < 8) ? ph : 23 - ph;
  const int i0 = itile * 64;
  const int tid = threadIdx.x;
  const int wv = tid >> 6;
  const int quad = (tid >> 4) & 3, colL = tid & 15;

  // q fragments with both biases
  ushort8 qw[2], qr[2];
  {
    const size_t qrow = (size_t)(b * SEQ + i0 + wv * 16 + colL) * 2048;
#pragma unroll
    for (int kh = 0; kh < 2; ++kh) {
      const int dof = hn * 64 + kh * 32 + quad * 8;
      const ushort8 qv = *(const ushort8*)&qk[qrow + dof];
      const float4 w0 = *(const float4*)&rwb[dof];
      const float4 w1 = *(const float4*)&rwb[dof + 4];
      const float4 r0 = *(const float4*)&rrb[dof];
      const float4 r1 = *(const float4*)&rrb[dof + 4];
      const float wb[8] = {w0.x, w0.y, w0.z, w0.w, w1.x, w1.y, w1.z, w1.w};
      const float rb[8] = {r0.x, r0.y, r0.z, r0.w, r1.x, r1.y, r1.z, r1.w};
#pragma unroll
      for (int e = 0; e < 8; ++e) {
        const float qf = bf2f(qv[e]);
        qw[kh][e] = f2bf(qf + wb[e]);
        qr[kh][e] = f2bf(qf + rb[e]);
      }
    }
  }

  f32x4 oacc[4] = {};
  float m_st[4], l_st[4];
#pragma unroll
  for (int r = 0; r < 4; ++r) {
    m_st[r] = -1e30f;
    l_st[r] = 0.f;
  }

  for (int j0 = 0; j0 <= i0; j0 += 64) {
    __syncthreads();  // prev-iter Ps/vs reads done before restage
    // stage k
#pragma unroll
    for (int rr = 0; rr < 2; ++rr) {
      const int c = rr * 256 + tid;
      const int j = c >> 3, dc = c & 7;
      *(ushort8*)&ks[j * 72 + dc * 8] = *(const ushort8*)&qk[
          (size_t)(b * SEQ + j0 + j) * 2048 + 1024 + hn * 64 + dc * 8];
    }
    // stage v (already transposed in global)
#pragma unroll
    for (int rr = 0; rr < 2; ++rr) {
      const int c = rr * 256 + tid;
      const int d = c >> 3, jc = c & 7;
      *(ushort8*)&vs[d * 72 + jc * 8] = *(const ushort8*)&vT[
          (size_t)(b * SEQ + hn * 64 + d) * 1024 + j0 + jc * 8];
    }
    // stage rp band
    const int pbase = SEQ - 64 - i0 + j0;
#pragma unroll
    for (int rr = 0; rr < 4; ++rr) {
      const int c = rr * 256 + tid;
      const int t = c >> 3, dc = c & 7;
      const int p = pbase + t;
      ushort8 rv;
      if (p < SEQ) {
        rv = *(const ushort8*)&rp[(size_t)p * 1024 + hn * 64 + dc * 8];
      } else {
#pragma unroll
        for (int e = 0; e < 8; ++e) rv[e] = 0;
      }
      *(ushort8*)&rs[t * 72 + dc * 8] = rv;
    }
    __syncthreads();

    // AC: 16x64 per wave
    f32x4 sAC[4] = {};
#pragma unroll
    for (int jt = 0; jt < 4; ++jt)
#pragma unroll
      for (int kh = 0; kh < 2; ++kh)
        sAC[jt] = mfma16(
            qw[kh],
            *(const ushort8*)&ks[(jt * 16 + colL) * 72 + kh * 32 + quad * 8],
            sAC[jt]);
    // BD band: only the 5 tiles this wave's rows need (tt = 3-wv .. 7-wv)
    f32x4 bd[5] = {};
#pragma unroll
    for (int u = 0; u < 5; ++u) {
      const int tt = 3 - wv + u;
#pragma unroll
      for (int kh = 0; kh < 2; ++kh)
        bd[u] = mfma16(
            qr[kh],
            *(const ushort8*)&rs[(tt * 16 + colL) * 72 + kh * 32 + quad * 8],
            bd[u]);
    }
    __syncthreads();  // all ks/rs reads complete before aliased writes

    // Btl (wave-private rows): stride 132 -> conflict-free scalar writes
#pragma unroll
    for (int u = 0; u < 5; ++u) {
      const int tt = 3 - wv + u;
#pragma unroll
      for (int e = 0; e < 4; ++e)
        Btl[(wv * 16 + quad * 4 + e) * 132 + tt * 16 + colL] = f2bf(bd[u][e]);
    }

    // gather diag + mask + online softmax; write P
#pragma unroll
    for (int r = 0; r < 4; ++r) {
      const int iLt = wv * 16 + quad * 4 + r;
      const int ig = i0 + iLt;
      float s[4];
#pragma unroll
      for (int jt = 0; jt < 4; ++jt) {
        const int jL = jt * 16 + colL;
        const float bdv = bf2f(Btl[iLt * 132 + 63 + jL - iLt]);
        s[jt] = (j0 + jL <= ig) ? (sAC[jt][r] + bdv) * 0.03125f : -1e30f;
      }
      float mx = fmaxf(fmaxf(s[0], s[1]), fmaxf(s[2], s[3]));
      mx = fmaxf(mx, __shfl_xor(mx, 1));
      mx = fmaxf(mx, __shfl_xor(mx, 2));
      mx = fmaxf(mx, __shfl_xor(mx, 4));
      mx = fmaxf(mx, __shfl_xor(mx, 8));
      const float m_new = fmaxf(m_st[r], mx);
      const float alpha = __expf(m_st[r] - m_new);
      float ps = 0.f;
#pragma unroll
      for (int jt = 0; jt < 4; ++jt) {
        const float pv = __expf(s[jt] - m_new);
        ps += pv;
        Ps[iLt * 72 + jt * 16 + colL] = f2bf(pv);
      }
      ps += __shfl_xor(ps, 1);
      ps += __shfl_xor(ps, 2);
      ps += __shfl_xor(ps, 4);
      ps += __shfl_xor(ps, 8);
      l_st[r] = l_st[r] * alpha + ps;
      m_st[r] = m_new;
#pragma unroll
      for (int dt = 0; dt < 4; ++dt) oacc[dt][r] *= alpha;
    }
    __syncthreads();  // Ps ready for all waves

    // PV: O += P @ V
#pragma unroll
    for (int dt = 0; dt < 4; ++dt)
#pragma unroll
      for (int kh = 0; kh < 2; ++kh)
        oacc[dt] = mfma16(
            *(const ushort8*)&Ps[(wv * 16 + colL) * 72 + kh * 32 + quad * 8],
            *(const ushort8*)&vs[(dt * 16 + colL) * 72 + kh * 32 + quad * 8],
            oacc[dt]);
  }

#pragma unroll
  for (int r = 0; r < 4; ++r) {
    const float invl = 1.0f / l_st[r];
    const size_t grow =
        (size_t)(b * SEQ + i0 + wv * 16 + quad * 4 + r) * 1024 + hn * 64;
#pragma unroll
    for (int dt = 0; dt < 4; ++dt)
      obuf[grow + dt * 16 + colL] = f2bf(oacc[dt][r] * invl);
  }
}

// ---------------------------------------------------------------------------
// LayerNorm over last dim (1024), in-place safe.
// ---------------------------------------------------------------------------
__global__ __launch_bounds__(256) void ln_kernel(const float* __restrict__ x,
                                                 const float* __restrict__ gamma,
                                                 const float* __restrict__ beta,
                                                 float* __restrict__ out) {
  const int row = blockIdx.x;
  const int tid = threadIdx.x;
  const float4 xv = *(const float4*)&x[(size_t)row * EMB + tid * 4];
  float sum = xv.x + xv.y + xv.z + xv.w;
  float ss = xv.x * xv.x + xv.y * xv.y + xv.z * xv.z + xv.w * xv.w;
#pragma unroll
  for (int off = 1; off < 64; off <<= 1) {
    sum += __shfl_xor(sum, off);
    ss += __shfl_xor(ss, off);
  }
  __shared__ float s1[4], s2[4];
  if ((tid & 63) == 0) {
    s1[tid >> 6] = sum;
    s2[tid >> 6] = ss;
  }
  __syncthreads();
  sum = s1[0] + s1[1] + s1[2] + s1[3];
  ss = s2[0] + s2[1] + s2[2] + s2[3];
  const float mu = sum * (1.f / EMB);
  const float var = ss * (1.f / EMB) - mu * mu;
  const float rstd = rsqrtf(var + LN_EPS);
  const float4 g = *(const float4*)&gamma[tid * 4];
  const float4 be = *(const float4*)&beta[tid * 4];
  float4 o;
  o.x = (xv.x - mu) * rstd * g.x + be.x;
  o.y = (xv.y - mu) * rstd * g.y + be.y;
  o.z = (xv.z - mu) * rstd * g.z + be.z;
  o.w = (xv.w - mu) * rstd * g.w + be.w;
  *(float4*)&out[(size_t)row * EMB + tid * 4] = o;
}

extern "C" void kernel_launch(void* const* d_in, const int* in_sizes, int n_in,
                              void* d_out, int out_size, void* d_ws,
                              size_t ws_size, hipStream_t stream) {
  const float* w = (const float*)d_in[0];
  const float* r = (const float*)d_in[1];
  const float* rwb = (const float*)d_in[2];
  const float* rrb = (const float*)d_in[3];
  // d_in[4] attn_mask: causality handled analytically
  const float* Wq = (const float*)d_in[5];
  const float* Wk = (const float*)d_in[6];
  const float* Wv = (const float*)d_in[7];
  const float* Wr = (const float*)d_in[8];
  const float* Wo = (const float*)d_in[9];
  const float* gamma = (const float*)d_in[10];
  const float* beta = (const float*)d_in[11];
  float* outp = (float*)d_out;

  char* wsb = (char*)d_ws;
  u16* wbf = (u16*)(wsb);                         // 8 MB  [0,8)
  u16* rbf = (u16*)(wsb + ((size_t)8 << 20));     // 2 MB  [8,10)
  u16* WqkvT = (u16*)(wsb + ((size_t)10 << 20));  // 6 MB  [10,16)
  u16* WrT = (u16*)(wsb + ((size_t)16 << 20));    // 2 MB  [16,18)
  u16* WoT = (u16*)(wsb + ((size_t)18 << 20));    // 2 MB  [18,20)
  u16* qk = (u16*)(wsb + ((size_t)20 << 20));     // 16 MB [20,36)
  u16* vT = (u16*)(wsb + ((size_t)36 << 20));     // 8 MB  [36,44)
  u16* rpb = (u16*)(wsb + ((size_t)44 << 20));    // 2 MB  [44,46)
  u16* obuf = (u16*)(wsb + ((size_t)10 << 20));   // 8 MB overlay [10,18)

  const dim3 blk(256);
  f2bf_fused<<<5120, blk, 0, stream>>>(w, r, wbf, rbf);
  transpose_f2bf5<<<dim3(32, 32, 5), blk, 0, stream>>>(Wq, Wk, Wv, Wr, Wo,
                                                       WqkvT, WrT, WoT);

  // QKV: cols<2048 -> qk (Nld=2048), cols>=2048 -> vT (transposed)
  gemm_bf16<2><<<dim3(24, 32), blk, 0, stream>>>(wbf, WqkvT, nullptr, qk, vT,
                                                 2048);
  gemm_bf16<1><<<dim3(8, 8), blk, 0, stream>>>(rbf, WrT, nullptr, rpb, nullptr,
                                               1024);

  attn_mfma<<<1024, blk, 0, stream>>>(qk, vT, rpb, rwb, rrb, obuf);

  gemm_bf16<0><<<dim3(8, 32), blk, 0, stream>>>(obuf, WoT, w, (void*)outp,
                                                nullptr, 1024);
  ln_kernel<<<BQ * SEQ, blk, 0, stream>>>(outp, gamma, beta, outp);
}

// Round 4
// 249.832 us; speedup vs baseline: 5.7042x; 1.1484x over previous
//
#include <hip/hip_runtime.h>
#include <math.h>

#define BQ 4
#define SEQ 1024
#define EMB 1024
#define NH 16
#define DH 64
#define LN_EPS 1e-3f

typedef unsigned short u16;
typedef __attribute__((ext_vector_type(8))) unsigned short ushort8;
typedef __attribute__((ext_vector_type(4))) unsigned short ushort4v;
typedef __attribute__((ext_vector_type(8))) __bf16 bf16x8;
typedef __attribute__((ext_vector_type(4))) float f32x4;

__device__ __forceinline__ u16 f2bf(float f) {
  union { float f; unsigned u; } v;
  v.f = f;
  unsigned u = v.u;
  u += 0x7FFF + ((u >> 16) & 1);  // RNE
  return (u16)(u >> 16);
}
__device__ __forceinline__ float bf2f(u16 h) {
  union { unsigned u; float f; } v;
  v.u = ((unsigned)h) << 16;
  return v.f;
}
__device__ __forceinline__ bf16x8 as_bf(ushort8 v) {
  union { ushort8 u; bf16x8 b; } x;
  x.u = v;
  return x.b;
}
__device__ __forceinline__ f32x4 mfma16(ushort8 a, ushort8 b, f32x4 c) {
  return __builtin_amdgcn_mfma_f32_16x16x32_bf16(as_bf(a), as_bf(b), c, 0, 0, 0);
}
__device__ __forceinline__ void gload16(const u16* g, u16* l) {
  __builtin_amdgcn_global_load_lds(
      (const __attribute__((address_space(1))) void*)g,
      (__attribute__((address_space(3))) void*)l, 16, 0, 0);
}

// ---------------------------------------------------------------------------
// Fused prep: blocks [0,5120) fp32->bf16 of w|r; blocks [5120,10240)
// transpose+convert the 5 weight matrices.
// ---------------------------------------------------------------------------
__global__ __launch_bounds__(256) void prep_kernel(
    const float* __restrict__ w, const float* __restrict__ r,
    const float* __restrict__ Wq, const float* __restrict__ Wk,
    const float* __restrict__ Wv, const float* __restrict__ Wr,
    const float* __restrict__ Wo, u16* __restrict__ wbf,
    u16* __restrict__ rbf, u16* __restrict__ WqkvT, u16* __restrict__ WrT,
    u16* __restrict__ WoT) {
  __shared__ u16 tile[32][33];
  const int bid = blockIdx.x;
  const int tid = threadIdx.x;
  if (bid < 5120) {
    const float* src = (bid < 4096) ? w : r;
    u16* dst = (bid < 4096) ? wbf : rbf;
    const int base = (bid < 4096) ? bid : bid - 4096;
    const int idx = (base * 256 + tid) * 4;
    const float4 v = *(const float4*)&src[idx];
    ushort4v o;
    o[0] = f2bf(v.x);
    o[1] = f2bf(v.y);
    o[2] = f2bf(v.z);
    o[3] = f2bf(v.w);
    *(ushort4v*)&dst[idx] = o;
  } else {
    const int t = bid - 5120;
    const int z = t >> 10;
    const int tt = t & 1023;
    const float* src = (z == 0) ? Wq : (z == 1) ? Wk : (z == 2) ? Wv
                       : (z == 3) ? Wr : Wo;
    u16* dst = (z < 3) ? (WqkvT + (size_t)z * 1024 * 1024)
               : (z == 3) ? WrT : WoT;
    const int k0 = (tt >> 5) * 32, n0 = (tt & 31) * 32;
    const int rr = tid >> 3, c4 = tid & 7;
    const float4 v =
        *(const float4*)&src[(size_t)(k0 + rr) * 1024 + n0 + c4 * 4];
    tile[rr][c4 * 4 + 0] = f2bf(v.x);
    tile[rr][c4 * 4 + 1] = f2bf(v.y);
    tile[rr][c4 * 4 + 2] = f2bf(v.z);
    tile[rr][c4 * 4 + 3] = f2bf(v.w);
    __syncthreads();
    ushort4v o;
#pragma unroll
    for (int e = 0; e < 4; ++e) o[e] = tile[c4 * 4 + e][rr];
    *(ushort4v*)&dst[(size_t)(n0 + rr) * 1024 + k0 + c4 * 4] = o;
  }
}

// ---------------------------------------------------------------------------
// Shared MFMA GEMM core: 128x128 tile, K=1024, BK=32, 4 waves.
// ---------------------------------------------------------------------------
__device__ __forceinline__ void gemm_core(const u16* __restrict__ A,
                                          const u16* __restrict__ Bt, int bm0,
                                          int bn0, u16* As, u16* Bs, int tid,
                                          f32x4 acc[4][4]) {
  const int quad = (tid >> 4) & 3, colL = tid & 15;
  const int wv = tid >> 6;
  const int wr = wv >> 1, wc = wv & 1;
  for (int k0 = 0; k0 < 1024; k0 += 32) {
#pragma unroll
    for (int rr = 0; rr < 2; ++rr) {
      const int c = rr * 256 + tid;
      const int row = c >> 2, kc = c & 3;
      gload16(&A[(size_t)(bm0 + row) * 1024 + k0 + kc * 8], &As[c * 8]);
      gload16(&Bt[(size_t)(bn0 + row) * 1024 + k0 + kc * 8], &Bs[c * 8]);
    }
    __syncthreads();
    ushort8 af[4], bf[4];
#pragma unroll
    for (int t = 0; t < 4; ++t) {
      af[t] = *(const ushort8*)&As[(wr * 64 + t * 16 + colL) * 32 + quad * 8];
      bf[t] = *(const ushort8*)&Bs[(wc * 64 + t * 16 + colL) * 32 + quad * 8];
    }
#pragma unroll
    for (int i = 0; i < 4; ++i)
#pragma unroll
      for (int j = 0; j < 4; ++j) acc[i][j] = mfma16(af[i], bf[j], acc[i][j]);
    __syncthreads();
  }
}

// ---------------------------------------------------------------------------
// Fused QKV + Rp GEMM. Blocks [0,768): w @ Wqkv -> qk (cols<2048) / vT
// (cols>=2048, transposed). Blocks [768,832): r @ Wr -> rpb.
// ---------------------------------------------------------------------------
__global__ __launch_bounds__(256) void gemm_qkvrp(
    const u16* __restrict__ wbf, const u16* __restrict__ WqkvT,
    const u16* __restrict__ rbf, const u16* __restrict__ WrT,
    u16* __restrict__ qk, u16* __restrict__ vT, u16* __restrict__ rpb) {
  __shared__ u16 As[128 * 32];
  __shared__ u16 Bs[128 * 32];
  const int bid = blockIdx.x;
  const int tid = threadIdx.x;
  const bool isR = (bid >= 768);
  const u16* A = isR ? rbf : wbf;
  const u16* Bt = isR ? WrT : WqkvT;
  const int bm0 = isR ? ((bid - 768) >> 3) * 128 : (bid / 24) * 128;
  const int bn0 = isR ? ((bid - 768) & 7) * 128 : (bid % 24) * 128;

  f32x4 acc[4][4] = {};
  gemm_core(A, Bt, bm0, bn0, As, Bs, tid, acc);

  const int quad = (tid >> 4) & 3, colL = tid & 15;
  const int wv = tid >> 6;
  const int wr = wv >> 1, wc = wv & 1;
  const bool vpart = !isR && (bn0 >= 2048);
#pragma unroll
  for (int i = 0; i < 4; ++i) {
    const int grow0 = bm0 + wr * 64 + i * 16 + quad * 4;
#pragma unroll
    for (int j = 0; j < 4; ++j) {
      const int gcol = bn0 + wc * 64 + j * 16 + colL;
      if (vpart) {
        const size_t base =
            ((size_t)(grow0 >> 10) * 1024 + (gcol - 2048)) * 1024 +
            (grow0 & 1023);
        ushort4v o;
#pragma unroll
        for (int e = 0; e < 4; ++e) o[e] = f2bf(acc[i][j][e]);
        *(ushort4v*)&vT[base] = o;
      } else {
        u16* dst = isR ? rpb : qk;
        const int Nld = isR ? 1024 : 2048;
#pragma unroll
        for (int e = 0; e < 4; ++e)
          dst[(size_t)(grow0 + e) * Nld + gcol] = f2bf(acc[i][j][e]);
      }
    }
  }
}

// ---------------------------------------------------------------------------
// Wo GEMM with fused residual (fp32 out, N=1024).
// ---------------------------------------------------------------------------
__global__ __launch_bounds__(256) void gemm_wo(const u16* __restrict__ A,
                                               const u16* __restrict__ Bt,
                                               const float* __restrict__ res,
                                               float* __restrict__ C) {
  __shared__ u16 As[128 * 32];
  __shared__ u16 Bs[128 * 32];
  const int tid = threadIdx.x;
  const int bm0 = blockIdx.y * 128, bn0 = blockIdx.x * 128;
  f32x4 acc[4][4] = {};
  gemm_core(A, Bt, bm0, bn0, As, Bs, tid, acc);
  const int quad = (tid >> 4) & 3, colL = tid & 15;
  const int wv = tid >> 6;
  const int wr = wv >> 1, wc = wv & 1;
#pragma unroll
  for (int i = 0; i < 4; ++i) {
    const int grow0 = bm0 + wr * 64 + i * 16 + quad * 4;
#pragma unroll
    for (int j = 0; j < 4; ++j) {
      const int gcol = bn0 + wc * 64 + j * 16 + colL;
#pragma unroll
      for (int e = 0; e < 4; ++e) {
        const size_t off = (size_t)(grow0 + e) * 1024 + gcol;
        C[off] = acc[i][j][e] + res[off];
      }
    }
  }
}

// ---------------------------------------------------------------------------
// MFMA flash attention, Transformer-XL rel-pos. 2 barriers/iter.
// LDS (52 KB, all single-buffered):
//   ks  [0,4096)      64x64  XOR-granule swizzled, filled by global_load_lds
//   vs  [4096,8192)   64x64  [d][j], swizzled, global_load_lds
//   rs  [8192,16384)  128x64 band, swizzled, global_load_lds
//   Btl [16384,21760) per-wave 16x84 (wave-private, no barrier)
//   Ps  [21760,26112) 64x68  (wave-private rows, no barrier)
// Swizzle: granule g of row r stored at slot g^(r&7); fragment reads are
// ds_read_b128 with 2-way-max bank aliasing (free per m136).
// ---------------------------------------------------------------------------
__global__ __launch_bounds__(256, 3) void attn_mfma(
    const u16* __restrict__ qk,  // [4096][2048]  q|k
    const u16* __restrict__ vT,  // [4096][1024]  [b*1024+hd][j]
    const u16* __restrict__ rp,  // [1024][1024]
    const float* __restrict__ rwb, const float* __restrict__ rrb,
    u16* __restrict__ obuf) {  // [4096][1024]
  __shared__ u16 smem[26112];
  u16* ks = smem;
  u16* vs = smem + 4096;
  u16* rs = smem + 8192;
  u16* Btl = smem + 16384;  // per-wave 16 rows x stride 84
  u16* Ps = smem + 21760;   // stride 68

  const int L = blockIdx.x;
  const int b = L & 3;
  const int hn = (L >> 2) & 15;
  const int ph = L >> 6;
  const int itile = (ph < 8) ? ph : 23 - ph;
  const int i0 = itile * 64;
  const int tid = threadIdx.x;
  const int wv = tid >> 6;
  const int quad = (tid >> 4) & 3, colL = tid & 15;
  // XOR-swizzled granule offsets (u16 units) for the two K-halves
  const int xo0 = ((quad) ^ (colL & 7)) * 8;
  const int xo1 = ((4 + quad) ^ (colL & 7)) * 8;

  // q fragments with both biases
  ushort8 qw[2], qr[2];
  {
    const size_t qrow = (size_t)(b * SEQ + i0 + wv * 16 + colL) * 2048;
#pragma unroll
    for (int kh = 0; kh < 2; ++kh) {
      const int dof = hn * 64 + kh * 32 + quad * 8;
      const ushort8 qv = *(const ushort8*)&qk[qrow + dof];
      const float4 w0 = *(const float4*)&rwb[dof];
      const float4 w1 = *(const float4*)&rwb[dof + 4];
      const float4 r0 = *(const float4*)&rrb[dof];
      const float4 r1 = *(const float4*)&rrb[dof + 4];
      const float wb[8] = {w0.x, w0.y, w0.z, w0.w, w1.x, w1.y, w1.z, w1.w};
      const float rb[8] = {r0.x, r0.y, r0.z, r0.w, r1.x, r1.y, r1.z, r1.w};
#pragma unroll
      for (int e = 0; e < 8; ++e) {
        const float qf = bf2f(qv[e]);
        qw[kh][e] = f2bf(qf + wb[e]);
        qr[kh][e] = f2bf(qf + rb[e]);
      }
    }
  }

  f32x4 oacc[4] = {};
  float m_st[4], l_st[4];
#pragma unroll
  for (int r = 0; r < 4; ++r) {
    m_st[r] = -1e30f;
    l_st[r] = 0.f;
  }

  for (int j0 = 0; j0 <= i0; j0 += 64) {
    __syncthreads();  // prev-iter ks/vs/rs reads (incl PV) complete
    // ---- async staging: ks, vs, rs via global_load_lds, XOR swizzle ----
#pragma unroll
    for (int rr = 0; rr < 2; ++rr) {
      const int c = rr * 256 + tid;
      const int row = c >> 3, gp = c & 7;
      const int g = gp ^ (row & 7);
      gload16(&qk[(size_t)(b * SEQ + j0 + row) * 2048 + 1024 + hn * 64 + g * 8],
              &ks[c * 8]);
    }
#pragma unroll
    for (int rr = 0; rr < 2; ++rr) {
      const int c = rr * 256 + tid;
      const int d = c >> 3, gp = c & 7;
      const int g = gp ^ (d & 7);
      gload16(&vT[(size_t)(b * SEQ + hn * 64 + d) * 1024 + j0 + g * 8],
              &vs[c * 8]);
    }
    const int pbase = SEQ - 64 - i0 + j0;
#pragma unroll
    for (int rr = 0; rr < 4; ++rr) {
      const int c = rr * 256 + tid;
      const int t = c >> 3, gp = c & 7;
      const int g = gp ^ (t & 7);
      int p = pbase + t;
      p = (p < SEQ) ? p : SEQ - 1;  // clamped rows are causally masked later
      gload16(&rp[(size_t)p * 1024 + hn * 64 + g * 8], &rs[c * 8]);
    }
    __syncthreads();  // vmcnt drained -> tiles ready

    // ---- AC: 16x64 per wave ----
    f32x4 sAC[4] = {};
#pragma unroll
    for (int jt = 0; jt < 4; ++jt) {
      const int rbase = (jt * 16 + colL) * 64;
      sAC[jt] = mfma16(qw[0], *(const ushort8*)&ks[rbase + xo0], sAC[jt]);
      sAC[jt] = mfma16(qw[1], *(const ushort8*)&ks[rbase + xo1], sAC[jt]);
    }
    // ---- BD band: 5 wave-private tiles (tt = 3-wv+u) ----
    f32x4 bd[5];
#pragma unroll
    for (int u = 0; u < 5; ++u) {
      const int rbase = ((3 - wv + u) * 16 + colL) * 64;
      f32x4 t = {};
      t = mfma16(qr[0], *(const ushort8*)&rs[rbase + xo0], t);
      t = mfma16(qr[1], *(const ushort8*)&rs[rbase + xo1], t);
      bd[u] = t;
    }
    // Btl (wave-private): row lr=quad*4+e, col u*16+colL, stride 84
    u16* btw = Btl + wv * 1344;
#pragma unroll
    for (int u = 0; u < 5; ++u)
#pragma unroll
      for (int e = 0; e < 4; ++e)
        btw[(quad * 4 + e) * 84 + u * 16 + colL] = f2bf(bd[u][e]);

    // ---- gather diag + mask + online softmax -> Ps (wave-private) ----
#pragma unroll
    for (int r = 0; r < 4; ++r) {
      const int lr = quad * 4 + r;
      const int iLt = wv * 16 + lr;
      const int ig = i0 + iLt;
      float s[4];
#pragma unroll
      for (int jt = 0; jt < 4; ++jt) {
        const int jL = jt * 16 + colL;
        const float bdv = bf2f(btw[lr * 83 + 15 + jL]);
        s[jt] = (j0 + jL <= ig) ? (sAC[jt][r] + bdv) * 0.03125f : -1e30f;
      }
      float mx = fmaxf(fmaxf(s[0], s[1]), fmaxf(s[2], s[3]));
      mx = fmaxf(mx, __shfl_xor(mx, 1));
      mx = fmaxf(mx, __shfl_xor(mx, 2));
      mx = fmaxf(mx, __shfl_xor(mx, 4));
      mx = fmaxf(mx, __shfl_xor(mx, 8));
      const float m_new = fmaxf(m_st[r], mx);
      const float alpha = __expf(m_st[r] - m_new);
      float ps = 0.f;
#pragma unroll
      for (int jt = 0; jt < 4; ++jt) {
        const float pv = __expf(s[jt] - m_new);
        ps += pv;
        Ps[iLt * 68 + jt * 16 + colL] = f2bf(pv);
      }
      ps += __shfl_xor(ps, 1);
      ps += __shfl_xor(ps, 2);
      ps += __shfl_xor(ps, 4);
      ps += __shfl_xor(ps, 8);
      l_st[r] = l_st[r] * alpha + ps;
      m_st[r] = m_new;
#pragma unroll
      for (int dt = 0; dt < 4; ++dt) oacc[dt][r] *= alpha;
    }

    // ---- PV: O += P @ V (Ps rows wave-private; vs staged this iter) ----
    const int prow = (wv * 16 + colL) * 68;
#pragma unroll
    for (int dt = 0; dt < 4; ++dt) {
      const int vbase = (dt * 16 + colL) * 64;
      oacc[dt] = mfma16(*(const ushort8*)&Ps[prow + quad * 8],
                        *(const ushort8*)&vs[vbase + xo0], oacc[dt]);
      oacc[dt] = mfma16(*(const ushort8*)&Ps[prow + 32 + quad * 8],
                        *(const ushort8*)&vs[vbase + xo1], oacc[dt]);
    }
  }

#pragma unroll
  for (int r = 0; r < 4; ++r) {
    const float invl = 1.0f / l_st[r];
    const size_t grow =
        (size_t)(b * SEQ + i0 + wv * 16 + quad * 4 + r) * 1024 + hn * 64;
#pragma unroll
    for (int dt = 0; dt < 4; ++dt)
      obuf[grow + dt * 16 + colL] = f2bf(oacc[dt][r] * invl);
  }
}

// ---------------------------------------------------------------------------
// LayerNorm over last dim (1024), in-place safe.
// ---------------------------------------------------------------------------
__global__ __launch_bounds__(256) void ln_kernel(const float* __restrict__ x,
                                                 const float* __restrict__ gamma,
                                                 const float* __restrict__ beta,
                                                 float* __restrict__ out) {
  const int row = blockIdx.x;
  const int tid = threadIdx.x;
  const float4 xv = *(const float4*)&x[(size_t)row * EMB + tid * 4];
  float sum = xv.x + xv.y + xv.z + xv.w;
  float ss = xv.x * xv.x + xv.y * xv.y + xv.z * xv.z + xv.w * xv.w;
#pragma unroll
  for (int off = 1; off < 64; off <<= 1) {
    sum += __shfl_xor(sum, off);
    ss += __shfl_xor(ss, off);
  }
  __shared__ float s1[4], s2[4];
  if ((tid & 63) == 0) {
    s1[tid >> 6] = sum;
    s2[tid >> 6] = ss;
  }
  __syncthreads();
  sum = s1[0] + s1[1] + s1[2] + s1[3];
  ss = s2[0] + s2[1] + s2[2] + s2[3];
  const float mu = sum * (1.f / EMB);
  const float var = ss * (1.f / EMB) - mu * mu;
  const float rstd = rsqrtf(var + LN_EPS);
  const float4 g = *(const float4*)&gamma[tid * 4];
  const float4 be = *(const float4*)&beta[tid * 4];
  float4 o;
  o.x = (xv.x - mu) * rstd * g.x + be.x;
  o.y = (xv.y - mu) * rstd * g.y + be.y;
  o.z = (xv.z - mu) * rstd * g.z + be.z;
  o.w = (xv.w - mu) * rstd * g.w + be.w;
  *(float4*)&out[(size_t)row * EMB + tid * 4] = o;
}

extern "C" void kernel_launch(void* const* d_in, const int* in_sizes, int n_in,
                              void* d_out, int out_size, void* d_ws,
                              size_t ws_size, hipStream_t stream) {
  const float* w = (const float*)d_in[0];
  const float* r = (const float*)d_in[1];
  const float* rwb = (const float*)d_in[2];
  const float* rrb = (const float*)d_in[3];
  // d_in[4] attn_mask: causality handled analytically
  const float* Wq = (const float*)d_in[5];
  const float* Wk = (const float*)d_in[6];
  const float* Wv = (const float*)d_in[7];
  const float* Wr = (const float*)d_in[8];
  const float* Wo = (const float*)d_in[9];
  const float* gamma = (const float*)d_in[10];
  const float* beta = (const float*)d_in[11];
  float* outp = (float*)d_out;

  char* wsb = (char*)d_ws;
  u16* wbf = (u16*)(wsb);                         // 8 MB  [0,8)
  u16* rbf = (u16*)(wsb + ((size_t)8 << 20));     // 2 MB  [8,10)
  u16* WqkvT = (u16*)(wsb + ((size_t)10 << 20));  // 6 MB  [10,16)
  u16* WrT = (u16*)(wsb + ((size_t)16 << 20));    // 2 MB  [16,18)
  u16* WoT = (u16*)(wsb + ((size_t)18 << 20));    // 2 MB  [18,20)
  u16* qk = (u16*)(wsb + ((size_t)20 << 20));     // 16 MB [20,36)
  u16* vT = (u16*)(wsb + ((size_t)36 << 20));     // 8 MB  [36,44)
  u16* rpb = (u16*)(wsb + ((size_t)44 << 20));    // 2 MB  [44,46)
  u16* obuf = (u16*)(wsb + ((size_t)10 << 20));   // 8 MB overlay [10,18):
                                                  // WqkvT/WrT dead post-gemm

  const dim3 blk(256);
  prep_kernel<<<10240, blk, 0, stream>>>(w, r, Wq, Wk, Wv, Wr, Wo, wbf, rbf,
                                         WqkvT, WrT, WoT);
  gemm_qkvrp<<<832, blk, 0, stream>>>(wbf, WqkvT, rbf, WrT, qk, vT, rpb);
  attn_mfma<<<1024, blk, 0, stream>>>(qk, vT, rpb, rwb, rrb, obuf);
  gemm_wo<<<dim3(8, 32), blk, 0, stream>>>(obuf, WoT, w, outp);
  ln_kernel<<<BQ * SEQ, blk, 0, stream>>>(outp, gamma, beta, outp);
}